// Round 1
// baseline (283.863 us; speedup 1.0000x reference)
//
#include <hip/hip_runtime.h>
#include <math.h>

#define NROWS  32768
#define CDIM   256
#define KCODES 1024
#define ZQ_ELEMS 8388608   // 32*256*32*32

// ws layout in floats (needs ~1.16 MB of ws):
#define CBT_OFF   0         // 262144 floats: cbT[d*1024+k]
#define ESQ_OFF   262144    // 1024 floats
#define ACC_OFF   263168    // 1 float (loss accumulator)
#define IDX_OFF   263200    // 32768 ints

// ---------------- prep: codebook transpose ----------------
__global__ __launch_bounds__(256) void transpose_cb_kernel(const float* __restrict__ cb,
                                                           float* __restrict__ cbT) {
    int tid = blockIdx.x * 256 + threadIdx.x;   // tid = d*1024 + k
    int d = tid >> 10;
    int k = tid & 1023;
    cbT[tid] = cb[k * CDIM + d];
}

// ---------------- prep: e_sq with numpy pairwise-sum semantics ----------------
__global__ __launch_bounds__(256) void esq_kernel(const float* __restrict__ cb,
                                                  float* __restrict__ esq) {
    int k = blockIdx.x * 256 + threadIdx.x;
    if (k >= KCODES) return;
    const float* p = cb + (size_t)k * CDIM;
    float half_[2];
    for (int h = 0; h < 2; ++h) {
        const float* q = p + h * 128;
        float r8[8];
#pragma unroll
        for (int j = 0; j < 8; ++j) { float v = q[j]; r8[j] = __fmul_rn(v, v); }
        for (int i = 8; i < 128; i += 8) {
#pragma unroll
            for (int j = 0; j < 8; ++j) {
                float v = q[i + j];
                r8[j] = __fadd_rn(r8[j], __fmul_rn(v, v));
            }
        }
        half_[h] = __fadd_rn(__fadd_rn(__fadd_rn(r8[0], r8[1]), __fadd_rn(r8[2], r8[3])),
                             __fadd_rn(__fadd_rn(r8[4], r8[5]), __fadd_rn(r8[6], r8[7])));
    }
    esq[k] = __fadd_rn(half_[0], half_[1]);
}

// ---------------- argmin over codes ----------------
// 1024 blocks x 256 threads. Block handles 32 rows x all 1024 codes.
// Thread (tr, tc): tr = tid>>5 owns rows tr*4..tr*4+3; tc = tid&31 owns 8 codes per 256-code tile.
__global__ __launch_bounds__(256, 2) void argmin_kernel(const float* __restrict__ z,
                                                        const float* __restrict__ cbT,
                                                        const float* __restrict__ esq,
                                                        float* __restrict__ out_idx_f,
                                                        int* __restrict__ out_idx_i) {
    __shared__ float z_t[CDIM][32];   // 32 KB, dim-major z tile (direct copy thanks to BCHW layout)
    __shared__ float e_t[32][256];    // 32 KB, dim-major codebook chunk (32 dims x 256 codes)
    __shared__ float zsq_s[32];

    const int tid = threadIdx.x;
    const int blk = blockIdx.x;                 // 0..1023
    const int b   = blk >> 5;                   // batch
    const int hw0 = (blk & 31) << 5;            // hw chunk start
    const float* zb = z + (size_t)b * 262144 + hw0;  // z[b][d][hw0+r] = zb[d*1024 + r]

    // stage z tile: z_t[d][r], coalesced 128B segments
    {
        int part = tid & 7;       // which float4 of the 32-float row
        int d0   = tid >> 3;      // 0..31
#pragma unroll
        for (int i = 0; i < 8; ++i) {
            int d = d0 + i * 32;
            float4 v = *reinterpret_cast<const float4*>(zb + (size_t)d * 1024 + part * 4);
            *reinterpret_cast<float4*>(&z_t[d][part * 4]) = v;
        }
    }
    __syncthreads();

    // z_sq per row, replicating numpy pairwise summation of fl(v*v)
    if (tid < 32) {
        float half_[2];
        for (int h = 0; h < 2; ++h) {
            float r8[8];
#pragma unroll
            for (int j = 0; j < 8; ++j) {
                float v = z_t[h * 128 + j][tid];
                r8[j] = __fmul_rn(v, v);
            }
            for (int i = 8; i < 128; i += 8) {
#pragma unroll
                for (int j = 0; j < 8; ++j) {
                    float v = z_t[h * 128 + i + j][tid];
                    r8[j] = __fadd_rn(r8[j], __fmul_rn(v, v));
                }
            }
            half_[h] = __fadd_rn(__fadd_rn(__fadd_rn(r8[0], r8[1]), __fadd_rn(r8[2], r8[3])),
                                 __fadd_rn(__fadd_rn(r8[4], r8[5]), __fadd_rn(r8[6], r8[7])));
        }
        zsq_s[tid] = __fadd_rn(half_[0], half_[1]);
    }
    __syncthreads();

    const int tc = tid & 31;
    const int tr = tid >> 5;

    float zsq[4];
#pragma unroll
    for (int r = 0; r < 4; ++r) zsq[r] = zsq_s[tr * 4 + r];

    float best_d[4];
    int   best_i[4];
#pragma unroll
    for (int r = 0; r < 4; ++r) { best_d[r] = INFINITY; best_i[r] = 0; }

    for (int ct = 0; ct < 4; ++ct) {           // 4 code tiles of 256
        float acc[4][8];
#pragma unroll
        for (int r = 0; r < 4; ++r)
#pragma unroll
            for (int j = 0; j < 8; ++j) acc[r][j] = 0.0f;

        for (int kc = 0; kc < CDIM; kc += 32) {
            __syncthreads();  // previous e_t reads complete
            {
                int rr = tid >> 3;   // dim row within chunk
                int p  = tid & 7;
                const float* src = cbT + (size_t)(kc + rr) * 1024 + ct * 256;
#pragma unroll
                for (int i = 0; i < 8; ++i) {
                    float4 v = *reinterpret_cast<const float4*>(src + (p + i * 8) * 4);
                    *reinterpret_cast<float4*>(&e_t[rr][(p + i * 8) * 4]) = v;
                }
            }
            __syncthreads();

#pragma unroll 4
            for (int kk = 0; kk < 32; ++kk) {
                float4 zt = *reinterpret_cast<const float4*>(&z_t[kc + kk][tr * 4]);
                float4 ea = *reinterpret_cast<const float4*>(&e_t[kk][tc * 8]);
                float4 eb = *reinterpret_cast<const float4*>(&e_t[kk][tc * 8 + 4]);
                float za[4] = {zt.x, zt.y, zt.z, zt.w};
                float ev[8] = {ea.x, ea.y, ea.z, ea.w, eb.x, eb.y, eb.z, eb.w};
#pragma unroll
                for (int r = 0; r < 4; ++r)
#pragma unroll
                    for (int j = 0; j < 8; ++j)
                        acc[r][j] = fmaf(za[r], ev[j], acc[r][j]);
            }
        }

        // distances for this tile: d = fl(fl(zsq + esq) - 2*dot), strict < keeps first min
        float eqv[8];
        {
            float4 e1 = *reinterpret_cast<const float4*>(esq + ct * 256 + tc * 8);
            float4 e2 = *reinterpret_cast<const float4*>(esq + ct * 256 + tc * 8 + 4);
            eqv[0] = e1.x; eqv[1] = e1.y; eqv[2] = e1.z; eqv[3] = e1.w;
            eqv[4] = e2.x; eqv[5] = e2.y; eqv[6] = e2.z; eqv[7] = e2.w;
        }
#pragma unroll
        for (int j = 0; j < 8; ++j) {
            int code = ct * 256 + tc * 8 + j;
#pragma unroll
            for (int r = 0; r < 4; ++r) {
                float t1 = __fadd_rn(zsq[r], eqv[j]);
                float dd = __fadd_rn(t1, __fmul_rn(-2.0f, acc[r][j]));
                if (dd < best_d[r]) { best_d[r] = dd; best_i[r] = code; }
            }
        }
    }

    // reduce across the 32 tc lanes (disjoint ascending code ranges; tie -> smaller index)
#pragma unroll
    for (int m = 16; m >= 1; m >>= 1) {
#pragma unroll
        for (int r = 0; r < 4; ++r) {
            float od = __shfl_xor(best_d[r], m, 64);
            int   oi = __shfl_xor(best_i[r], m, 64);
            if (od < best_d[r] || (od == best_d[r] && oi < best_i[r])) {
                best_d[r] = od; best_i[r] = oi;
            }
        }
    }

    if (tc == 0) {
#pragma unroll
        for (int r = 0; r < 4; ++r) {
            int n = blk * 32 + tr * 4 + r;
            out_idx_f[n] = (float)best_i[r];
            out_idx_i[n] = best_i[r];
        }
    }
}

// ---------------- gather z_q + loss ----------------
// 1024 blocks: blk = b*32 + chunk*8 + cgrp ; thread owns one hw, 32 channels
__global__ __launch_bounds__(256) void gather_kernel(const float* __restrict__ z,
                                                     const float* __restrict__ cbT,
                                                     const int* __restrict__ idx_i,
                                                     float* __restrict__ out0,
                                                     float* __restrict__ accum) {
    int tid   = threadIdx.x;
    int blk   = blockIdx.x;
    int b     = blk >> 5;
    int chunk = (blk >> 3) & 3;
    int cgrp  = blk & 7;
    int hw = chunk * 256 + tid;
    int n  = b * 1024 + hw;
    int code = idx_i[n];
    float lsum = 0.0f;
    size_t base = (size_t)b * 262144 + hw;
#pragma unroll 4
    for (int c = cgrp * 32; c < cgrp * 32 + 32; ++c) {
        float zq = cbT[(size_t)c * 1024 + code];
        size_t off = base + (size_t)c * 1024;
        float zv = z[off];
        out0[off] = zq;
        float dfr = zv - zq;
        lsum = fmaf(dfr, dfr, lsum);
    }
#pragma unroll
    for (int m = 32; m >= 1; m >>= 1) lsum += __shfl_down(lsum, m, 64);
    __shared__ float red[4];
    int wv = tid >> 6, ln = tid & 63;
    if (ln == 0) red[wv] = lsum;
    __syncthreads();
    if (tid == 0) atomicAdd(accum, (red[0] + red[1]) + (red[2] + red[3]));
}

__global__ void finalize_kernel(const float* __restrict__ accum, float* __restrict__ out_loss) {
    // vq_loss = mse + 0.25*mse = 1.25 * sum / 8388608
    out_loss[0] = accum[0] * (1.25f / 8388608.0f);
}

extern "C" void kernel_launch(void* const* d_in, const int* in_sizes, int n_in,
                              void* d_out, int out_size, void* d_ws, size_t ws_size,
                              hipStream_t stream) {
    const float* z  = (const float*)d_in[0];   // [32,256,32,32]
    const float* cb = (const float*)d_in[1];   // [1024,256]

    float* ws    = (float*)d_ws;
    float* cbT   = ws + CBT_OFF;
    float* esq   = ws + ESQ_OFF;
    float* accum = ws + ACC_OFF;
    int*   idx_i = (int*)(ws + IDX_OFF);

    float* out0     = (float*)d_out;          // z_q_st  [8388608]
    float* out_loss = out0 + ZQ_ELEMS;        // scalar
    float* out_idxf = out0 + ZQ_ELEMS + 1;    // indices as float [32768]

    hipMemsetAsync(accum, 0, sizeof(float), stream);
    transpose_cb_kernel<<<1024, 256, 0, stream>>>(cb, cbT);
    esq_kernel<<<4, 256, 0, stream>>>(cb, esq);
    argmin_kernel<<<1024, 256, 0, stream>>>(z, cbT, esq, out_idxf, idx_i);
    gather_kernel<<<1024, 256, 0, stream>>>(z, cbT, idx_i, out0, accum);
    finalize_kernel<<<1, 1, 0, stream>>>(accum, out_loss);
}